// Round 1
// 220.881 us; speedup vs baseline: 1.0162x; 1.0162x over previous
//
#include <hip/hip_runtime.h>
#include <hip/hip_bf16.h>

// Problem constants (B=8, H=W=32, C=768, heads=12, hd=64)
#define BATCH 8
#define SEQ   1024      // H*W
#define CH    768
#define NH    12
#define HD    64
#define BH    96        // BATCH*NH
#define N_QKV 2304      // 3*CH

#define LOG2E 1.44269504088896f

typedef __attribute__((ext_vector_type(8))) short bfrag;   // 8 bf16 (4 VGPRs)
typedef __attribute__((ext_vector_type(4))) short short4v; // 4 bf16 (8B)
typedef __attribute__((ext_vector_type(4))) float ffrag;   // MFMA C/D

__device__ __forceinline__ short f2bf(float x) {
    __hip_bfloat16 h = __float2bfloat16(x);
    return *reinterpret_cast<short*>(&h);
}
__device__ __forceinline__ float bf2f(short b) {
    __hip_bfloat16 h;
    *reinterpret_cast<short*>(&h) = b;
    return __bfloat162float(h);
}
__device__ __forceinline__ void split2(float x, short& hi, short& lo) {
    short h = f2bf(x);
    hi = h;
    lo = f2bf(x - bf2f(h));
}
__device__ __forceinline__ void async_copy16(void* lds, const void* g) {
    __builtin_amdgcn_global_load_lds(
        (const __attribute__((address_space(1))) void*)g,
        (__attribute__((address_space(3))) void*)lds, 16, 0, 0);
}

// ---------------------------------------------------------------------------
// Fused prepass:
//   blocks [0,512):    x fp32 -> Xh bf16 (hi only)
//   blocks [512,2240): w_qkv transpose -> WqhT bf16 (hi only; 1-term GEMM)
//   blocks [2240,2816): w_proj transpose+split -> WphT/WplT (3-term proj)
// ---------------------------------------------------------------------------
__global__ __launch_bounds__(256) void prep(
    const float* __restrict__ x,
    const float* __restrict__ w_qkv, const float* __restrict__ w_proj,
    short* __restrict__ Xh,
    short* __restrict__ WqhT,
    short* __restrict__ WphT, short* __restrict__ WplT)
{
    __shared__ float ts[32][33];
    const int tid = threadIdx.x;
    const int bid = blockIdx.x;

    if (bid < 512) {                    // ---- x -> bf16 hi ----
        const int n4 = (BATCH * SEQ * CH) / 4;
        for (int i = bid * 256 + tid; i < n4; i += 512 * 256) {
            float4 f = ((const float4*)x)[i];
            short4v h;
            h[0] = f2bf(f.x); h[1] = f2bf(f.y); h[2] = f2bf(f.z); h[3] = f2bf(f.w);
            ((short4v*)Xh)[i] = h;
        }
        return;
    }
    if (bid < 2240) {                   // ---- w_qkv transpose, hi only ----
        int t = bid - 512;
        const int bx = t % 72, by = t / 72;
        const int r0 = by * 32, c0 = bx * 32;
        #pragma unroll
        for (int i = 0; i < 4; ++i) {
            int idx = tid + i * 256;
            int rr = idx >> 5, cc = idx & 31;
            ts[rr][cc] = w_qkv[(size_t)(r0 + rr) * N_QKV + c0 + cc];
        }
        __syncthreads();
        #pragma unroll
        for (int i = 0; i < 4; ++i) {
            int idx = tid + i * 256;
            int rr = idx >> 5, cc = idx & 31;
            WqhT[(size_t)(c0 + rr) * CH + r0 + cc] = f2bf(ts[cc][rr]);
        }
        return;
    }
    // ---- w_proj transpose + split ----
    {
        int t = bid - 2240;
        const int bx = t % 24, by = t / 24;
        const int r0 = by * 32, c0 = bx * 32;
        #pragma unroll
        for (int i = 0; i < 4; ++i) {
            int idx = tid + i * 256;
            int rr = idx >> 5, cc = idx & 31;
            ts[rr][cc] = w_proj[(size_t)(r0 + rr) * CH + c0 + cc];
        }
        __syncthreads();
        #pragma unroll
        for (int i = 0; i < 4; ++i) {
            int idx = tid + i * 256;
            int rr = idx >> 5, cc = idx & 31;
            short h, l;
            split2(ts[cc][rr], h, l);
            WphT[(size_t)(c0 + rr) * CH + r0 + cc] = h;
            WplT[(size_t)(c0 + rr) * CH + r0 + cc] = l;
        }
    }
}

// ---------------------------------------------------------------------------
// 1-term GEMM core (AhBh): 2 LDS buffers (32 KB). 128x128 tile, BK=64.
// ---------------------------------------------------------------------------
__device__ __forceinline__ void gemm_core1(
    short* lds,                                    // 2 * 8192 shorts
    const short* __restrict__ Ah, const short* __restrict__ BhT,
    int m0, int n0, ffrag acc[4][4])
{
    const int tid = threadIdx.x;
    const int wave = tid >> 6, lane = tid & 63;
    const int quad = lane >> 4, l16 = lane & 15;
    const int wm = (wave & 1) * 64, wn = (wave >> 1) * 64;

    const int arr  = wave >> 1;          // 0 = A, 1 = B
    const int half = wave & 1;           // row half
    const short* src = arr ? BhT : Ah;
    const int row0 = (arr ? n0 : m0) + half * 64;
    const size_t lane_off = (size_t)(lane >> 3) * CH + (size_t)((lane & 7) ^ (lane >> 3)) * 8;
    const short* sbase = src + (size_t)row0 * CH + lane_off;
    short* ldsw = lds + arr * 8192 + half * 4096;

    for (int c = 0; c < 12; ++c) {
        __syncthreads();
        #pragma unroll
        for (int i = 0; i < 8; ++i)
            async_copy16(ldsw + i * 512, sbase + (size_t)i * 8 * CH + c * 64);
        __syncthreads();

        #pragma unroll
        for (int kc = 0; kc < 2; ++kc) {
            bfrag ah[4], bh[4];
            const int xs = ((kc * 4 + quad) ^ (l16 & 7)) * 8;
            #pragma unroll
            for (int i = 0; i < 4; ++i) {
                ah[i] = *(const bfrag*)&lds[(wm + i * 16 + l16) * 64 + xs];
                bh[i] = *(const bfrag*)&lds[8192 + (wn + i * 16 + l16) * 64 + xs];
            }
            #pragma unroll
            for (int mi = 0; mi < 4; ++mi)
                #pragma unroll
                for (int ni = 0; ni < 4; ++ni)
                    acc[mi][ni] = __builtin_amdgcn_mfma_f32_16x16x32_bf16(ah[mi], bh[ni], acc[mi][ni], 0, 0, 0);
        }
    }
}

// ---------------------------------------------------------------------------
// 3-term GEMM core (AhBh + AhBl + AlBh): proj only.
// ---------------------------------------------------------------------------
__device__ __forceinline__ void gemm_core3(
    short* lds,                                    // 4 * 8192 shorts
    const short* __restrict__ Ah, const short* __restrict__ Al,
    const short* __restrict__ BhT, const short* __restrict__ BlT,
    int m0, int n0, ffrag acc[4][4])
{
    const int tid = threadIdx.x;
    const int wave = tid >> 6, lane = tid & 63;
    const int quad = lane >> 4, l16 = lane & 15;
    const int wm = (wave & 1) * 64, wn = (wave >> 1) * 64;

    const short* src;
    int row0;
    if (wave == 0)      { src = Ah;  row0 = m0; }
    else if (wave == 1) { src = Al;  row0 = m0; }
    else if (wave == 2) { src = BhT; row0 = n0; }
    else                { src = BlT; row0 = n0; }
    const size_t lane_off = (size_t)(lane >> 3) * CH + (size_t)((lane & 7) ^ (lane >> 3)) * 8;
    const short* sbase = src + (size_t)row0 * CH + lane_off;
    short* ldsw = lds + wave * 8192;

    for (int c = 0; c < 12; ++c) {
        __syncthreads();
        #pragma unroll
        for (int i = 0; i < 16; ++i)
            async_copy16(ldsw + i * 512, sbase + (size_t)i * 8 * CH + c * 64);
        __syncthreads();

        #pragma unroll
        for (int kc = 0; kc < 2; ++kc) {
            bfrag ah[4], al[4], bh[4], bl[4];
            const int xs = ((kc * 4 + quad) ^ (l16 & 7)) * 8;
            #pragma unroll
            for (int i = 0; i < 4; ++i) {
                int ra = (wm + i * 16 + l16) * 64 + xs;
                int rb = (wn + i * 16 + l16) * 64 + xs;
                ah[i] = *(const bfrag*)&lds[ra];
                al[i] = *(const bfrag*)&lds[8192 + ra];
                bh[i] = *(const bfrag*)&lds[16384 + rb];
                bl[i] = *(const bfrag*)&lds[24576 + rb];
            }
            #pragma unroll
            for (int mi = 0; mi < 4; ++mi)
                #pragma unroll
                for (int ni = 0; ni < 4; ++ni) {
                    acc[mi][ni] = __builtin_amdgcn_mfma_f32_16x16x32_bf16(ah[mi], bh[ni], acc[mi][ni], 0, 0, 0);
                    acc[mi][ni] = __builtin_amdgcn_mfma_f32_16x16x32_bf16(ah[mi], bl[ni], acc[mi][ni], 0, 0, 0);
                    acc[mi][ni] = __builtin_amdgcn_mfma_f32_16x16x32_bf16(al[mi], bh[ni], acc[mi][ni], 0, 0, 0);
                }
        }
    }
}

// ---------------------------------------------------------------------------
// GEMM 1: qkv = x @ w_qkv + bias (1-term).
// XCD tiling 16m x 9n: per-XCD working set A ~0.6MB + B ~1.76MB < 4MB L2.
// ---------------------------------------------------------------------------
__global__ __launch_bounds__(256) void gemm_qkv_mfma(
    const short* __restrict__ Xh,
    const short* __restrict__ WhT,
    const float* __restrict__ bias,
    short* __restrict__ qh, short* __restrict__ kh, short* __restrict__ vT)
{
    __shared__ short lds[2 * 8192];
    const int id  = blockIdx.x;          // 0..1151
    const int xcd = id & 7;
    const int per = id >> 3;             // 0..143
    const int mi_ = per / 9, ni_ = per % 9;
    const int m0 = ((xcd & 3) * 16 + mi_) * 128;
    const int n0 = ((xcd >> 2) * 9 + ni_) * 128;
    const int which = n0 / CH;           // tile-uniform (768 % 128 == 0)

    ffrag acc[4][4];
    #pragma unroll
    for (int i = 0; i < 4; ++i)
        #pragma unroll
        for (int j = 0; j < 4; ++j) acc[i][j] = (ffrag){0.f, 0.f, 0.f, 0.f};

    gemm_core1(lds, Xh, WhT, m0, n0, acc);

    const int tid = threadIdx.x;
    const int wave = tid >> 6, lane = tid & 63;
    const int quad = lane >> 4, l16 = lane & 15;
    const int wm = (wave & 1) * 64, wn = (wave >> 1) * 64;
    const int b = m0 >> 10;              // tile-uniform (128 | 1024)

    #pragma unroll
    for (int ni = 0; ni < 4; ++ni) {
        int n = n0 + wn + ni * 16 + l16;
        float bv = bias[n];
        int nin = n - which * CH;        // 0..767
        int head = nin >> 6, d = nin & 63;
        #pragma unroll
        for (int mi = 0; mi < 4; ++mi) {
            if (which == 2) {
                int s_base = (m0 & 1023) + wm + mi * 16 + quad * 4;
                short4v pk;
                #pragma unroll
                for (int r = 0; r < 4; ++r) pk[r] = f2bf(acc[mi][ni][r] + bv);
                *(short4v*)&vT[((size_t)(b * NH + head) * HD + d) * SEQ + s_base] = pk;
            } else {
                const float scale = (which == 0) ? 0.125f * LOG2E : 1.0f;
                short* dst = (which == 0) ? qh : kh;
                #pragma unroll
                for (int r = 0; r < 4; ++r) {
                    int m = m0 + wm + mi * 16 + quad * 4 + r;
                    int s = m & 1023;
                    dst[((size_t)(b * NH + head) * SEQ + s) * HD + d] =
                        f2bf((acc[mi][ni][r] + bv) * scale);
                }
            }
        }
    }
}

// ---------------------------------------------------------------------------
// GEMM 2: out = ao @ w_proj + bias -> fp32 d_out (3-term, XCD swizzle)
// ---------------------------------------------------------------------------
__global__ __launch_bounds__(256) void gemm_proj_mfma(
    const short* __restrict__ Ah, const short* __restrict__ Al,
    const short* __restrict__ WhT, const short* __restrict__ WlT,
    const float* __restrict__ bias, float* __restrict__ out)
{
    __shared__ short lds[4 * 8192];
    const int id  = blockIdx.x;          // 0..383
    const int xcd = id & 7;
    const int per = id >> 3;             // 0..47
    const int m0 = (xcd * 8 + per / 6) * 128;
    const int n0 = (per % 6) * 128;

    ffrag acc[4][4];
    #pragma unroll
    for (int i = 0; i < 4; ++i)
        #pragma unroll
        for (int j = 0; j < 4; ++j) acc[i][j] = (ffrag){0.f, 0.f, 0.f, 0.f};

    gemm_core3(lds, Ah, Al, WhT, WlT, m0, n0, acc);

    const int tid = threadIdx.x;
    const int wave = tid >> 6, lane = tid & 63;
    const int quad = lane >> 4, l16 = lane & 15;
    const int wm = (wave & 1) * 64, wn = (wave >> 1) * 64;

    #pragma unroll
    for (int ni = 0; ni < 4; ++ni) {
        int n = n0 + wn + ni * 16 + l16;
        float bv = bias[n];
        #pragma unroll
        for (int mi = 0; mi < 4; ++mi)
            #pragma unroll
            for (int r = 0; r < 4; ++r) {
                int m = m0 + wm + mi * 16 + quad * 4 + r;
                out[(size_t)m * CH + n] = acc[mi][ni][r] + bv;
            }
    }
}

// ---------------------------------------------------------------------------
// Flash attention, S^T form, stride-68 P buffer.
// THIS ROUND (T14 + T5):
//   - K/V staging switched from single-buffered global_load_lds (which forces
//     a vmcnt(0) drain at the barrier, exposing full load latency per chunk)
//     to double-buffered REGISTER staging: chunk c+1's global->reg loads are
//     issued right after the first barrier of chunk c and land in LDS at the
//     top of chunk c+1. Plain register loads survive across s_barrier, so
//     the HBM/L2 latency hides under the whole compute phase (T14, +17% on
//     attn per catalog). LDS layout is byte-identical to the DMA layout, so
//     all read paths / swizzles are unchanged. LDS size unchanged -> still
//     3 blocks/CU.
//   - s_setprio(1) around S^T MFMA pairs and PV MFMA quads (T5).
// ---------------------------------------------------------------------------
__global__ __launch_bounds__(256, 3) void attn_kernel(
    const short* __restrict__ qh,
    const short* __restrict__ kh_g, const short* __restrict__ vT_g,
    const float* __restrict__ rph,   // (63, 64) fp32
    const float* __restrict__ rpw,   // (63, 64) fp32
    short* __restrict__ aoh, short* __restrict__ aol)   // (8192, 768) split bf16
{
    const int fid   = blockIdx.x;        // 0..767
    const int xcd   = fid & 7;
    const int inner = fid >> 3;          // 0..95
    const int s0    = (inner & 7) * 128; // 8 consecutive blocks share bh
    const int bh    = xcd * 12 + (inner >> 3);

    const int tid  = threadIdx.x;
    const int wave = tid >> 6;
    const int lane = tid & 63;
    const int quad = lane >> 4;
    const int l16  = lane & 15;

    __shared__ short Kh[64 * 64];        // [key][d] swizzled, 8 KB
    __shared__ short Vth[64 * 64];       // [d][key] swizzled, 8 KB
    __shared__ short Th[128][68];        // rel-h table, 17408 B
    __shared__ short Tw_Ps[128 * 68];    // Tw (setup) then P [query][key]; 17408 B

    const size_t bh_koff = (size_t)bh * SEQ * HD;
    const size_t bh_voff = (size_t)bh * HD * SEQ;
    const size_t klane = (size_t)(lane >> 3) * HD + (size_t)((lane & 7) ^ (lane >> 3)) * 8;
    const size_t vlane = (size_t)(lane >> 3) * SEQ + (size_t)((lane & 7) ^ (lane >> 3)) * 8;

    const short* kbase = kh_g + bh_koff + klane;   // + (c*64 + i*8)*HD
    const short* vbase = vT_g + bh_voff + vlane;   // + (i*8)*SEQ + c*64
    const int i0 = wave * 2;                        // this wave's two 8-row groups
    short* KhW0 = Kh  + i0 * 512 + lane * 8;        // == DMA dest (base + lane*16B)
    short* VtW0 = Vth + i0 * 512 + lane * 8;

    // ---- prefetch chunk 0 into reg set A (overlaps rel-table setup) ----
    int4 kA0, kA1, vA0, vA1, kB0, kB1, vB0, vB1;
    kA0 = *(const int4*)(kbase + (size_t)(i0 * 8) * HD);
    kA1 = *(const int4*)(kbase + (size_t)(i0 * 8 + 8) * HD);
    vA0 = *(const int4*)(vbase + (size_t)(i0 * 8) * SEQ);
    vA1 = *(const int4*)(vbase + (size_t)(i0 * 8 + 8) * SEQ);

    // ---- Q fragments (B-operand in S^T = K.Q^T) ----
    bfrag qfh[2][2];
    #pragma unroll
    for (int g = 0; g < 2; ++g) {
        const size_t qrow = ((size_t)bh * SEQ + s0 + wave * 32 + g * 16 + l16) * HD;
        #pragma unroll
        for (int kc = 0; kc < 2; ++kc)
            qfh[g][kc] = *(const bfrag*)(qh + qrow + kc * 32 + quad * 8);
    }

    // ---- rel tables: T[q][r] = log2e * (q . rel[r]) ----
    #pragma unroll
    for (int table = 0; table < 2; ++table) {
        const float* tbl = table ? rpw : rph;
        #pragma unroll
        for (int n0r = 0; n0r < 64; n0r += 16) {
            int r = n0r + l16;
            bfrag bfr[2];
            #pragma unroll
            for (int kc = 0; kc < 2; ++kc) {
                if (r < 63) {
                    const float* trow = tbl + (size_t)r * HD + kc * 32 + quad * 8;
                    float4 f0 = *(const float4*)(trow);
                    float4 f1 = *(const float4*)(trow + 4);
                    float xs[8] = {f0.x, f0.y, f0.z, f0.w, f1.x, f1.y, f1.z, f1.w};
                    #pragma unroll
                    for (int j = 0; j < 8; ++j) bfr[kc][j] = f2bf(xs[j]);
                } else {
                    #pragma unroll
                    for (int j = 0; j < 8; ++j) bfr[kc][j] = 0;
                }
            }
            #pragma unroll
            for (int g = 0; g < 2; ++g) {
                ffrag acc = {0.f, 0.f, 0.f, 0.f};
                acc = __builtin_amdgcn_mfma_f32_16x16x32_bf16(qfh[g][0], bfr[0], acc, 0, 0, 0);
                acc = __builtin_amdgcn_mfma_f32_16x16x32_bf16(qfh[g][1], bfr[1], acc, 0, 0, 0);
                int row = wave * 32 + g * 16 + quad * 4;
                #pragma unroll
                for (int reg = 0; reg < 4; ++reg) {
                    short v = f2bf(acc[reg] * 8.0f);
                    if (table) Tw_Ps[(row + reg) * 68 + n0r + l16] = v;
                    else       Th[row + reg][n0r + l16] = v;
                }
            }
        }
    }

    // ---- hoist Tw (chunk-invariant): wq = g*16+l16, wk = p*16+quad*4+reg ----
    float tw_r[2][2][4];
    #pragma unroll
    for (int g = 0; g < 2; ++g) {
        int qloc = wave * 32 + g * 16 + l16;
        int wq = g * 16 + l16;
        #pragma unroll
        for (int p = 0; p < 2; ++p)
            #pragma unroll
            for (int reg = 0; reg < 4; ++reg)
                tw_r[g][p][reg] = bf2f(Tw_Ps[qloc * 68 + (wq - (p * 16 + quad * 4 + reg) + 31)]);
    }
    const int hq_w = (s0 >> 5) + wave;   // wave-uniform

    // ---- state ----
    float l_part[2] = {0.f, 0.f};
    ffrag Ot[2][4];
    #pragma unroll
    for (int g = 0; g < 2; ++g)
        #pragma unroll
        for (int t = 0; t < 4; ++t) Ot[g][t] = (ffrag){0.f, 0.f, 0.f, 0.f};

    // ---- chunk body: write cur regs to LDS, prefetch next, compute ----
    auto chunk = [&](int c, const int4& ck0, const int4& ck1,
                     const int4& cv0, const int4& cv1,
                     int4& nk0, int4& nk1, int4& nv0, int4& nv1) {
        __syncthreads();              // previous chunk's LDS reads complete
        if (c < 15) {                 // issue next chunk's loads (non-blocking)
            const int cn = c + 1;
            nk0 = *(const int4*)(kbase + (size_t)(cn * 64 + i0 * 8) * HD);
            nk1 = *(const int4*)(kbase + (size_t)(cn * 64 + i0 * 8 + 8) * HD);
            nv0 = *(const int4*)(vbase + (size_t)(i0 * 8) * SEQ + cn * 64);
            nv1 = *(const int4*)(vbase + (size_t)(i0 * 8 + 8) * SEQ + cn * 64);
        }
        *(int4*)KhW0         = ck0;   // same bytes/addresses as the old DMA
        *(int4*)(KhW0 + 512) = ck1;
        *(int4*)VtW0         = cv0;
        *(int4*)(VtW0 + 512) = cv1;
        __syncthreads();              // LDS writes visible

        // ---- Th for this chunk: hk in {2c, 2c+1}; 4 scalar reads ----
        float th_r[2][2];
        #pragma unroll
        for (int g = 0; g < 2; ++g) {
            int qloc = wave * 32 + g * 16 + l16;
            th_r[g][0] = bf2f(Th[qloc][hq_w - 2 * c + 31]);
            th_r[g][1] = bf2f(Th[qloc][hq_w - 2 * c - 1 + 31]);
        }

        // ---- S^T = K.Q^T with rel-seeded C; p = exp2; b64 P store ----
        #pragma unroll
        for (int kt = 0; kt < 4; ++kt) {
            bfrag kbh[2];             // A-operand (K rows)
            #pragma unroll
            for (int kc = 0; kc < 2; ++kc) {
                int xs = ((kc * 4 + quad) ^ (l16 & 7)) * 8;
                kbh[kc] = *(const bfrag*)&Kh[(kt * 16 + l16) * 64 + xs];
            }
            const int hp = kt >> 1, wp = kt & 1;
            #pragma unroll
            for (int g = 0; g < 2; ++g) {
                ffrag acc;
                #pragma unroll
                for (int reg = 0; reg < 4; ++reg)
                    acc[reg] = th_r[g][hp] + tw_r[g][wp][reg];
                __builtin_amdgcn_s_setprio(1);
                acc = __builtin_amdgcn_mfma_f32_16x16x32_bf16(kbh[0], qfh[g][0], acc, 0, 0, 0);
                acc = __builtin_amdgcn_mfma_f32_16x16x32_bf16(kbh[1], qfh[g][1], acc, 0, 0, 0);
                __builtin_amdgcn_s_setprio(0);
                short4v pk;
                #pragma unroll
                for (int reg = 0; reg < 4; ++reg) {
                    float p = exp2f(acc[reg]);
                    l_part[g] += p;
                    pk[reg] = f2bf(p);
                }
                *(short4v*)&Tw_Ps[(wave * 32 + g * 16 + l16) * 68 + kt * 16 + quad * 4] = pk;
            }
        }

        // ---- P A-frags (own-wave rows; two b64 reads per frag) ----
        bfrag pf[2][2];
        #pragma unroll
        for (int g = 0; g < 2; ++g)
            #pragma unroll
            for (int kc2 = 0; kc2 < 2; ++kc2) {
                int base = (wave * 32 + g * 16 + l16) * 68 + kc2 * 32 + quad * 8;
                short4v lo = *(const short4v*)&Tw_Ps[base];
                short4v hi = *(const short4v*)&Tw_Ps[base + 4];
                bfrag p;
                #pragma unroll
                for (int j = 0; j < 4; ++j) { p[j] = lo[j]; p[j + 4] = hi[j]; }
                pf[g][kc2] = p;
            }

        // ---- PV: O += P @ V ----
        #pragma unroll
        for (int t = 0; t < 4; ++t) {
            int d = t * 16 + l16;
            int x0 = ((0 + quad) ^ (l16 & 7)) * 8;
            int x1 = ((4 + quad) ^ (l16 & 7)) * 8;
            bfrag vh0 = *(const bfrag*)&Vth[d * 64 + x0];
            bfrag vh1 = *(const bfrag*)&Vth[d * 64 + x1];
            __builtin_amdgcn_s_setprio(1);
            #pragma unroll
            for (int g = 0; g < 2; ++g) {
                Ot[g][t] = __builtin_amdgcn_mfma_f32_16x16x32_bf16(pf[g][0], vh0, Ot[g][t], 0, 0, 0);
                Ot[g][t] = __builtin_amdgcn_mfma_f32_16x16x32_bf16(pf[g][1], vh1, Ot[g][t], 0, 0, 0);
            }
            __builtin_amdgcn_s_setprio(0);
        }
    };

    for (int cc = 0; cc < 8; ++cc) {
        chunk(2 * cc,     kA0, kA1, vA0, vA1, kB0, kB1, vB0, vB1);
        chunk(2 * cc + 1, kB0, kB1, vB0, vB1, kA0, kA1, vA0, vA1);
    }

    // ---- epilogue: reduce l across quads, broadcast, split-bf16 store ----
    {
        int b = bh / NH, head = bh % NH;
        #pragma unroll
        for (int g = 0; g < 2; ++g) {
            float r = l_part[g];
            r += __shfl_xor(r, 16, 64);
            r += __shfl_xor(r, 32, 64);
            float invl = 1.f / r;     // valid for query (g, l16)
            float inv[4];
            #pragma unroll
            for (int reg = 0; reg < 4; ++reg)
                inv[reg] = __shfl(invl, quad * 4 + reg, 16);
            #pragma unroll
            for (int t = 0; t < 4; ++t) {
                #pragma unroll
                for (int reg = 0; reg < 4; ++reg) {
                    int s_ = s0 + wave * 32 + g * 16 + quad * 4 + reg;
                    int d = t * 16 + l16;
                    size_t idx = ((size_t)(b * SEQ + s_)) * CH + head * HD + d;
                    short h, l;
                    split2(Ot[g][t][reg] * inv[reg], h, l);
                    aoh[idx] = h;
                    aol[idx] = l;
                }
            }
        }
    }
}

// ---------------------------------------------------------------------------
extern "C" void kernel_launch(void* const* d_in, const int* in_sizes, int n_in,
                              void* d_out, int out_size, void* d_ws, size_t ws_size,
                              hipStream_t stream) {
    const float* x       = (const float*)d_in[0];
    const float* w_qkv   = (const float*)d_in[1];
    const float* b_qkv   = (const float*)d_in[2];
    const float* rph     = (const float*)d_in[3];
    const float* rpw     = (const float*)d_in[4];
    const float* w_proj  = (const float*)d_in[5];
    const float* b_proj  = (const float*)d_in[6];
    float* out = (float*)d_out;

    const size_t NTOK = (size_t)BATCH * SEQ;        // 8192
    const size_t XSZ  = NTOK * CH;                  // 6291456
    const size_t WQSZ = (size_t)N_QKV * CH;         // 1769472
    const size_t WPSZ = (size_t)CH * CH;            // 589824
    short* Xh   = (short*)d_ws;
    short* AoL  = Xh + XSZ;                          // attn-out lo buffer
    short* WqhT = AoL + XSZ;
    short* WphT = WqhT + WQSZ;
    short* WplT = WphT + WPSZ;
    short* qh = WplT + WPSZ;
    short* kh = qh + XSZ;
    short* vT = kh + XSZ;
    // attention output hi aliases Xh (X consumed by gemm_qkv before attn runs)
    short* aoh = Xh;
    short* aol = AoL;

    prep<<<dim3(2816), 256, 0, stream>>>(x, w_qkv, w_proj,
                                         Xh, WqhT, WphT, WplT);
    gemm_qkv_mfma<<<dim3(1152), 256, 0, stream>>>(Xh, WqhT, b_qkv,
                                                  qh, kh, vT);
    attn_kernel<<<dim3(768), 256, 0, stream>>>(qh, kh, vT,
                                               rph, rpw, aoh, aol);
    gemm_proj_mfma<<<dim3(384), 256, 0, stream>>>(aoh, aol, WphT, WplT,
                                                  b_proj, out);
}